// Round 4
// baseline (24004.720 us; speedup 1.0000x reference)
//
#include <hip/hip_runtime.h>
#include <hip/hip_bf16.h>

// Problem constants
#define T_TOK 6272      // B*D*H*W tokens (2*16*14*14)
#define CDIM  768
#define NTOK  392       // tokens per window (8*7*7)
#define NWIN  16        // total windows (B=2 * 8)
#define NHEADS 24
#define HDIM  32
#define QSCALE 0.17677669529663687f  // 32^-0.5

__device__ __forceinline__ float gelu_f(float x) {
    return 0.5f * x * (1.0f + erff(x * 0.70710678118654752f));
}

// ---------------------------------------------------------------------------
// (B,C,D,H,W) f32 -> X[t][c] f32, t = ((b*16+d)*14+h)*14+w
// grid (98, 24, 2), block (32, 8); per-b transpose of [768][3136] -> [3136][768]
__global__ __launch_bounds__(256) void k_transpose_in(const float* __restrict__ x,
                                                      float* __restrict__ X) {
    __shared__ float tile[32][33];
    int b  = blockIdx.z;
    int s0 = blockIdx.x * 32, c0 = blockIdx.y * 32;
    int tx = threadIdx.x, ty = threadIdx.y;
#pragma unroll
    for (int r = 0; r < 4; ++r) {
        int c = c0 + ty + r * 8;
        int s = s0 + tx;
        tile[ty + r * 8][tx] = x[((size_t)b * 768 + c) * 3136 + s];
    }
    __syncthreads();
#pragma unroll
    for (int r = 0; r < 4; ++r) {
        int s = s0 + ty + r * 8;
        int c = c0 + tx;
        X[((size_t)b * 3136 + s) * 768 + c] = tile[tx][ty + r * 8];
    }
}

// ---------------------------------------------------------------------------
// LayerNorm over C=768. mode 0: row=token (identity). mode 1: output row is
// window-layout (wi*392+n), source gathered from image layout. mode 2: same
// with shift roll(-4,-3,-3) folded into the gather. (LN is per-token, so
// LN-then-gather == gather-then-LN.)
__global__ __launch_bounds__(256) void k_layernorm(const float* __restrict__ X,
                                                   float* __restrict__ Y,
                                                   const float* __restrict__ g,
                                                   const float* __restrict__ bta,
                                                   int mode) {
    int row = blockIdx.x;
    int src = row;
    if (mode != 0) {
        int wi = row / NTOK, n = row % NTOK;
        int b = wi >> 3, rem = wi & 7;
        int wd = rem >> 2, wh = (rem >> 1) & 1, ww = rem & 1;
        int dn = n / 49, r2 = n % 49, hn = r2 / 7, wn = r2 % 7;
        int d = wd * 8 + dn, h = wh * 7 + hn, w = ww * 7 + wn;
        if (mode == 2) { d = (d + 4) & 15; h = (h + 3) % 14; w = (w + 3) % 14; }
        src = (b * 16 + d) * 196 + h * 14 + w;
    }
    const float* xr = X + (size_t)src * CDIM;
    int tid = threadIdx.x;
    float v0 = xr[tid], v1 = xr[tid + 256], v2 = xr[tid + 512];
    float s = v0 + v1 + v2;
    float q = v0 * v0 + v1 * v1 + v2 * v2;
    __shared__ float red[8];
#pragma unroll
    for (int off = 32; off > 0; off >>= 1) {
        s += __shfl_down(s, off);
        q += __shfl_down(q, off);
    }
    int lane = tid & 63, wv = tid >> 6;
    if (lane == 0) { red[wv] = s; red[4 + wv] = q; }
    __syncthreads();
    float ts = red[0] + red[1] + red[2] + red[3];
    float tq = red[4] + red[5] + red[6] + red[7];
    float mu  = ts * (1.0f / 768.0f);
    float var = tq * (1.0f / 768.0f) - mu * mu;
    float rstd = rsqrtf(var + 1e-5f);
    float* yr = Y + (size_t)row * CDIM;
    yr[tid]       = (v0 - mu) * rstd * g[tid]       + bta[tid];
    yr[tid + 256] = (v1 - mu) * rstd * g[tid + 256] + bta[tid + 256];
    yr[tid + 512] = (v2 - mu) * rstd * g[tid + 512] + bta[tid + 512];
}

// ---------------------------------------------------------------------------
// C[M,N] = act(A[M,K] @ W[N,K]^T + bias), all f32.
// remap 0: plain rows; remap 1/2: scatter window-layout rows back to image
// layout (2 = roll-back by +(4,3,3) folded in), always with ld 768. accum: +=.
// 64x64x16 tile, 256 threads, 4x4 microtile.
__global__ __launch_bounds__(256) void k_gemm(const float* __restrict__ A,
                                              const float* __restrict__ W,
                                              const float* __restrict__ bias,
                                              float* __restrict__ C,
                                              int M, int N, int K,
                                              int act, int remap, int accum) {
    __shared__ float As[16][64];
    __shared__ float Bs[16][64];
    int tid = threadIdx.x;
    int m0 = blockIdx.y * 64, n0 = blockIdx.x * 64;
    int lrow = tid >> 2;        // 0..63
    int lk   = (tid & 3) * 4;   // 0,4,8,12
    const float* aptr = A + (size_t)(m0 + lrow) * K + lk;
    const float* wptr = W + (size_t)(n0 + lrow) * K + lk;
    int tx = tid & 15, ty = tid >> 4;
    float acc[4][4] = {};
    for (int kt = 0; kt < K; kt += 16) {
        float4 av = *(const float4*)(aptr + kt);
        float4 wv4 = *(const float4*)(wptr + kt);
        As[lk + 0][lrow] = av.x;
        As[lk + 1][lrow] = av.y;
        As[lk + 2][lrow] = av.z;
        As[lk + 3][lrow] = av.w;
        Bs[lk + 0][lrow] = wv4.x;
        Bs[lk + 1][lrow] = wv4.y;
        Bs[lk + 2][lrow] = wv4.z;
        Bs[lk + 3][lrow] = wv4.w;
        __syncthreads();
#pragma unroll
        for (int k = 0; k < 16; ++k) {
            float4 a = *(const float4*)&As[k][ty * 4];
            float4 b = *(const float4*)&Bs[k][tx * 4];
            float avv[4] = {a.x, a.y, a.z, a.w};
            float bvv[4] = {b.x, b.y, b.z, b.w};
#pragma unroll
            for (int i = 0; i < 4; ++i)
#pragma unroll
                for (int j = 0; j < 4; ++j)
                    acc[i][j] += avv[i] * bvv[j];
        }
        __syncthreads();
    }
    float bvals[4];
#pragma unroll
    for (int j = 0; j < 4; ++j) bvals[j] = bias[n0 + tx * 4 + j];
#pragma unroll
    for (int i = 0; i < 4; ++i) {
        int r = m0 + ty * 4 + i;
        size_t orow;
        if (remap == 0) {
            orow = (size_t)r * N;
        } else {
            int wi = r / NTOK, n = r % NTOK;
            int b = wi >> 3, rem = wi & 7;
            int wd = rem >> 2, wh = (rem >> 1) & 1, ww = rem & 1;
            int dn = n / 49, r2 = n % 49, hn = r2 / 7, wn = r2 % 7;
            int d = wd * 8 + dn, h = wh * 7 + hn, w = ww * 7 + wn;
            if (remap == 2) { d = (d + 4) & 15; h = (h + 3) % 14; w = (w + 3) % 14; }
            orow = (size_t)((b * 16 + d) * 196 + h * 14 + w) * CDIM;
        }
#pragma unroll
        for (int j = 0; j < 4; ++j) {
            float v = acc[i][j] + bvals[j];
            if (act) v = gelu_f(v);
            int col = n0 + tx * 4 + j;
            if (accum) C[orow + col] += v;
            else       C[orow + col] = v;
        }
    }
}

// ---------------------------------------------------------------------------
// Attention: one block per (window, head). K staged in LDS (pad 33).
// 4 waves, each handles query rows i = wv, wv+4, ...
__global__ __launch_bounds__(256) void k_attn(const float* __restrict__ QKV,
                                              const float* __restrict__ rpb,
                                              const int* __restrict__ rpi,
                                              float* __restrict__ AO,
                                              int shifted) {
    int wi   = blockIdx.x / NHEADS;
    int head = blockIdx.x % NHEADS;
    int wbase = wi * NTOK;
    __shared__ float Ks[NTOK * 33];
    __shared__ float Ps[4][NTOK];
    __shared__ float Qs[4][HDIM];
    int tid = threadIdx.x;
    for (int idx = tid; idx < NTOK * HDIM; idx += 256) {
        int j = idx >> 5, d = idx & 31;
        Ks[j * 33 + d] = QKV[(size_t)(wbase + j) * 2304 + 768 + head * 32 + d];
    }
    __syncthreads();
    int lane = tid & 63, wv = tid >> 6;
    int rem = wi & 7;
    int wd = rem >> 2, wh = (rem >> 1) & 1, ww = rem & 1;

    for (int i = wv; i < NTOK; i += 4) {   // 98 iterations, uniform across waves
        if (lane < HDIM)
            Qs[wv][lane] = QKV[(size_t)(wbase + i) * 2304 + head * 32 + lane];
        __syncthreads();
        float q[HDIM];
#pragma unroll
        for (int d = 0; d < HDIM; ++d) q[d] = Qs[wv][d];

        int rid_i = 0;
        if (shifted) {
            int dn = i / 49, r2 = i % 49, hn = r2 / 7, wn = r2 % 7;
            int d = wd * 8 + dn, h = wh * 7 + hn, w = ww * 7 + wn;
            int di = (d < 8) ? 0 : (d < 12 ? 1 : 2);
            int hi = (h < 7) ? 0 : (h < 11 ? 1 : 2);
            int wj = (w < 7) ? 0 : (w < 11 ? 1 : 2);
            rid_i = (di * 3 + hi) * 3 + wj;
        }
        float sreg[7];
        float smax = -1e30f;
#pragma unroll
        for (int t = 0; t < 7; ++t) {
            int j = lane + t * 64;
            float sc = -1e30f;
            if (j < NTOK) {
                const float* kr = Ks + j * 33;
                float acc = 0.f;
#pragma unroll
                for (int d = 0; d < HDIM; ++d) acc += q[d] * kr[d];
                acc *= QSCALE;
                acc += rpb[(size_t)rpi[i * NTOK + j] * NHEADS + head];
                if (shifted) {
                    int dn = j / 49, r2 = j % 49, hn = r2 / 7, wn = r2 % 7;
                    int d = wd * 8 + dn, h = wh * 7 + hn, w = ww * 7 + wn;
                    int dj = (d < 8) ? 0 : (d < 12 ? 1 : 2);
                    int hj = (h < 7) ? 0 : (h < 11 ? 1 : 2);
                    int wj = (w < 7) ? 0 : (w < 11 ? 1 : 2);
                    if ((dj * 3 + hj) * 3 + wj != rid_i) acc -= 100.0f;
                }
                sc = acc;
            }
            sreg[t] = sc;
            smax = fmaxf(smax, sc);
        }
#pragma unroll
        for (int off = 32; off > 0; off >>= 1) smax = fmaxf(smax, __shfl_xor(smax, off));
        float ssum = 0.f;
#pragma unroll
        for (int t = 0; t < 7; ++t) {
            int j = lane + t * 64;
            if (j < NTOK) {
                float e = __expf(sreg[t] - smax);
                Ps[wv][j] = e;
                ssum += e;
            }
        }
#pragma unroll
        for (int off = 32; off > 0; off >>= 1) ssum += __shfl_xor(ssum, off);
        float inv = 1.0f / ssum;
        // P @ V
        int d = lane & 31, half = lane >> 5;
        const float* vb = QKV + (size_t)wbase * 2304 + 1536 + head * 32 + d;
        float acc = 0.f;
        for (int j = half; j < NTOK; j += 2) acc += Ps[wv][j] * vb[(size_t)j * 2304];
        acc += __shfl_xor(acc, 32);
        if (lane < 32)
            AO[(size_t)(wbase + i) * CDIM + head * 32 + d] = acc * inv;
    }
}

// ---------------------------------------------------------------------------
// Head conv2: (T,64) @ (2,64)^T + b -> gelu -> O2[t*2+p]
__global__ __launch_bounds__(256) void k_head_c2(const float* __restrict__ Y64,
                                                 const float* __restrict__ w2,
                                                 const float* __restrict__ b2,
                                                 float* __restrict__ O2) {
    int idx = blockIdx.x * 256 + threadIdx.x;
    if (idx >= T_TOK * 2) return;
    int t = idx >> 1, p = idx & 1;
    const float* yr = Y64 + (size_t)t * 64;
    float acc = b2[p];
#pragma unroll
    for (int o = 0; o < 64; ++o) acc += yr[o] * w2[p * 64 + o];
    O2[idx] = gelu_f(acc);
}

// score * weight, layout (B,2,D,H,W), *** float32 out ***
__global__ __launch_bounds__(256) void k_final(const float* __restrict__ O2,
                                               float* __restrict__ out) {
    int idx = blockIdx.x * 256 + threadIdx.x;
    if (idx >= 2 * 2 * 3136) return;
    int b = idx / 6272;
    int p = (idx / 3136) & 1;
    int s = idx % 3136;
    int t = b * 3136 + s;
    out[idx] = O2[t * 2 + p] * O2[(size_t)T_TOK * 2 + t * 2 + p];
}

// ---------------------------------------------------------------------------
extern "C" void kernel_launch(void* const* d_in, const int* in_sizes, int n_in,
                              void* d_out, int out_size, void* d_ws, size_t ws_size,
                              hipStream_t stream) {
    const float* x     = (const float*)d_in[0];
    const float* n1_g  = (const float*)d_in[1];
    const float* n1_b  = (const float*)d_in[2];
    const float* qkv_w = (const float*)d_in[3];
    const float* qkv_b = (const float*)d_in[4];
    const float* proj_w= (const float*)d_in[5];
    const float* proj_b= (const float*)d_in[6];
    const float* rpb   = (const float*)d_in[7];
    const float* n2_g  = (const float*)d_in[8];
    const float* n2_b  = (const float*)d_in[9];
    const float* fc1_w = (const float*)d_in[10];
    const float* fc1_b = (const float*)d_in[11];
    const float* fc2_w = (const float*)d_in[12];
    const float* fc2_b = (const float*)d_in[13];
    const float* hln_g = (const float*)d_in[14];
    const float* hln_b = (const float*)d_in[15];
    const float* c1_w  = (const float*)d_in[16];
    const float* c1_b  = (const float*)d_in[17];
    const float* c2_w  = (const float*)d_in[18];
    const float* c2_b  = (const float*)d_in[19];
    const int*   rpi   = (const int*)d_in[20];

    // ws layout (fp32): X | XW(=attn-out) | BIG(qkv 2304 / mlp 3072 cols) | Y64 | O2
    float* ws  = (float*)d_ws;
    float* X   = ws;
    float* XW  = X   + (size_t)T_TOK * CDIM;
    float* BIG = XW  + (size_t)T_TOK * CDIM;
    float* Y64 = BIG + (size_t)T_TOK * 3072;
    float* O2  = Y64 + (size_t)T_TOK * 64;   // total ~117 MB

    for (int br = 0; br < 2; ++br) {
        k_transpose_in<<<dim3(98, 24, 2), dim3(32, 8), 0, stream>>>(x, X);
        for (int bl = 0; bl < 2; ++bl) {
            int pb = br * 2 + bl;
            int shifted = bl;
            k_layernorm<<<T_TOK, 256, 0, stream>>>(X, XW, n1_g + pb * 768, n1_b + pb * 768, shifted ? 2 : 1);
            k_gemm<<<dim3(2304 / 64, 98), 256, 0, stream>>>(XW, qkv_w + (size_t)pb * 2304 * 768,
                                                            qkv_b + pb * 2304, BIG,
                                                            T_TOK, 2304, 768, 0, 0, 0);
            k_attn<<<NWIN * NHEADS, 256, 0, stream>>>(BIG, rpb + (size_t)pb * 2535 * 24, rpi, XW, shifted);
            k_gemm<<<dim3(768 / 64, 98), 256, 0, stream>>>(XW, proj_w + (size_t)pb * 768 * 768,
                                                           proj_b + pb * 768, X,
                                                           T_TOK, 768, 768, 0, shifted ? 2 : 1, 1);
            k_layernorm<<<T_TOK, 256, 0, stream>>>(X, XW, n2_g + pb * 768, n2_b + pb * 768, 0);
            k_gemm<<<dim3(3072 / 64, 98), 256, 0, stream>>>(XW, fc1_w + (size_t)pb * 3072 * 768,
                                                            fc1_b + pb * 3072, BIG,
                                                            T_TOK, 3072, 768, 1, 0, 0);
            k_gemm<<<dim3(768 / 64, 98), 256, 0, stream>>>(BIG, fc2_w + (size_t)pb * 768 * 3072,
                                                           fc2_b + pb * 768, X,
                                                           T_TOK, 768, 3072, 0, 0, 1);
        }
        k_layernorm<<<T_TOK, 256, 0, stream>>>(X, XW, hln_g + br * 768, hln_b + br * 768, 0);
        k_gemm<<<dim3(1, 98), 256, 0, stream>>>(XW, c1_w + (size_t)br * 64 * 768,
                                                c1_b + br * 64, Y64,
                                                T_TOK, 64, 768, 1, 0, 0);
        k_head_c2<<<(T_TOK * 2 + 255) / 256, 256, 0, stream>>>(Y64, c2_w + br * 128, c2_b + br * 2,
                                                               O2 + (size_t)br * T_TOK * 2);
    }
    k_final<<<(2 * 2 * 3136 + 255) / 256, 256, 0, stream>>>(O2, (float*)d_out);
}

// Round 5
// 9999.770 us; speedup vs baseline: 2.4005x; 2.4005x over previous
//
#include <hip/hip_runtime.h>
#include <hip/hip_bf16.h>

// Problem constants
#define T_TOK 6272      // B*D*H*W tokens (2*16*14*14)
#define CDIM  768
#define NTOK  392       // tokens per window (8*7*7)
#define NWIN  16        // total windows (B=2 * 8)
#define NHEADS 24
#define HDIM  32
#define QSCALE 0.17677669529663687f  // 32^-0.5

typedef unsigned short ushort_t;

__device__ __forceinline__ float bf2f(ushort_t h) {
    union { unsigned int u; float f; } v; v.u = ((unsigned int)h) << 16; return v.f;
}
__device__ __forceinline__ float gelu_f(float x) {
    return 0.5f * x * (1.0f + erff(x * 0.70710678118654752f));
}

// ---------------------------------------------------------------------------
// (B,C,D,H,W) f32 -> X[t][c] f32, t = ((b*16+d)*14+h)*14+w
__global__ __launch_bounds__(256) void k_transpose_in(const float* __restrict__ x,
                                                      float* __restrict__ X) {
    __shared__ float tile[32][33];
    int b  = blockIdx.z;
    int s0 = blockIdx.x * 32, c0 = blockIdx.y * 32;
    int tx = threadIdx.x, ty = threadIdx.y;
#pragma unroll
    for (int r = 0; r < 4; ++r) {
        int c = c0 + ty + r * 8;
        int s = s0 + tx;
        tile[ty + r * 8][tx] = x[((size_t)b * 768 + c) * 3136 + s];
    }
    __syncthreads();
#pragma unroll
    for (int r = 0; r < 4; ++r) {
        int s = s0 + ty + r * 8;
        int c = c0 + tx;
        X[((size_t)b * 3136 + s) * 768 + c] = tile[tx][ty + r * 8];
    }
}

// ---------------------------------------------------------------------------
// LayerNorm over C=768. mode 0: identity rows. mode 1: output row is
// window-layout, gathered. mode 2: same with shift roll(-4,-3,-3) folded in.
__global__ __launch_bounds__(256) void k_layernorm(const float* __restrict__ X,
                                                   float* __restrict__ Y,
                                                   const float* __restrict__ g,
                                                   const float* __restrict__ bta,
                                                   int mode) {
    int row = blockIdx.x;
    int src = row;
    if (mode != 0) {
        int wi = row / NTOK, n = row % NTOK;
        int b = wi >> 3, rem = wi & 7;
        int wd = rem >> 2, wh = (rem >> 1) & 1, ww = rem & 1;
        int dn = n / 49, r2 = n % 49, hn = r2 / 7, wn = r2 % 7;
        int d = wd * 8 + dn, h = wh * 7 + hn, w = ww * 7 + wn;
        if (mode == 2) { d = (d + 4) & 15; h = (h + 3) % 14; w = (w + 3) % 14; }
        src = (b * 16 + d) * 196 + h * 14 + w;
    }
    const float* xr = X + (size_t)src * CDIM;
    int tid = threadIdx.x;
    float v0 = xr[tid], v1 = xr[tid + 256], v2 = xr[tid + 512];
    float s = v0 + v1 + v2;
    float q = v0 * v0 + v1 * v1 + v2 * v2;
    __shared__ float red[8];
#pragma unroll
    for (int off = 32; off > 0; off >>= 1) {
        s += __shfl_down(s, off);
        q += __shfl_down(q, off);
    }
    int lane = tid & 63, wv = tid >> 6;
    if (lane == 0) { red[wv] = s; red[4 + wv] = q; }
    __syncthreads();
    float ts = red[0] + red[1] + red[2] + red[3];
    float tq = red[4] + red[5] + red[6] + red[7];
    float mu  = ts * (1.0f / 768.0f);
    float var = tq * (1.0f / 768.0f) - mu * mu;
    float rstd = rsqrtf(var + 1e-5f);
    float* yr = Y + (size_t)row * CDIM;
    yr[tid]       = (v0 - mu) * rstd * g[tid]       + bta[tid];
    yr[tid + 256] = (v1 - mu) * rstd * g[tid + 256] + bta[tid + 256];
    yr[tid + 512] = (v2 - mu) * rstd * g[tid + 512] + bta[tid + 512];
}

// ---------------------------------------------------------------------------
// C[M,N] = act(A[M,K] @ W[N,K]^T + bias), all f32.
// remap 0: plain rows; remap 1/2: scatter window rows to image layout
// (2 = roll-back +(4,3,3) folded). accum: +=. 64x64x16 tile, 4x4 microtile.
__global__ __launch_bounds__(256) void k_gemm(const float* __restrict__ A,
                                              const float* __restrict__ W,
                                              const float* __restrict__ bias,
                                              float* __restrict__ C,
                                              int M, int N, int K,
                                              int act, int remap, int accum) {
    __shared__ float As[16][64];
    __shared__ float Bs[16][64];
    int tid = threadIdx.x;
    int m0 = blockIdx.y * 64, n0 = blockIdx.x * 64;
    int lrow = tid >> 2;        // 0..63
    int lk   = (tid & 3) * 4;   // 0,4,8,12
    const float* aptr = A + (size_t)(m0 + lrow) * K + lk;
    const float* wptr = W + (size_t)(n0 + lrow) * K + lk;
    int tx = tid & 15, ty = tid >> 4;
    float acc[4][4] = {};
    for (int kt = 0; kt < K; kt += 16) {
        float4 av = *(const float4*)(aptr + kt);
        float4 wv4 = *(const float4*)(wptr + kt);
        As[lk + 0][lrow] = av.x;
        As[lk + 1][lrow] = av.y;
        As[lk + 2][lrow] = av.z;
        As[lk + 3][lrow] = av.w;
        Bs[lk + 0][lrow] = wv4.x;
        Bs[lk + 1][lrow] = wv4.y;
        Bs[lk + 2][lrow] = wv4.z;
        Bs[lk + 3][lrow] = wv4.w;
        __syncthreads();
#pragma unroll
        for (int k = 0; k < 16; ++k) {
            float4 a = *(const float4*)&As[k][ty * 4];
            float4 b = *(const float4*)&Bs[k][tx * 4];
            float avv[4] = {a.x, a.y, a.z, a.w};
            float bvv[4] = {b.x, b.y, b.z, b.w};
#pragma unroll
            for (int i = 0; i < 4; ++i)
#pragma unroll
                for (int j = 0; j < 4; ++j)
                    acc[i][j] += avv[i] * bvv[j];
        }
        __syncthreads();
    }
    float bvals[4];
#pragma unroll
    for (int j = 0; j < 4; ++j) bvals[j] = bias[n0 + tx * 4 + j];
#pragma unroll
    for (int i = 0; i < 4; ++i) {
        int r = m0 + ty * 4 + i;
        size_t orow;
        if (remap == 0) {
            orow = (size_t)r * N;
        } else {
            int wi = r / NTOK, n = r % NTOK;
            int b = wi >> 3, rem = wi & 7;
            int wd = rem >> 2, wh = (rem >> 1) & 1, ww = rem & 1;
            int dn = n / 49, r2 = n % 49, hn = r2 / 7, wn = r2 % 7;
            int d = wd * 8 + dn, h = wh * 7 + hn, w = ww * 7 + wn;
            if (remap == 2) { d = (d + 4) & 15; h = (h + 3) % 14; w = (w + 3) % 14; }
            orow = (size_t)((b * 16 + d) * 196 + h * 14 + w) * CDIM;
        }
#pragma unroll
        for (int j = 0; j < 4; ++j) {
            float v = acc[i][j] + bvals[j];
            if (act) v = gelu_f(v);
            int col = n0 + tx * 4 + j;
            if (accum) C[orow + col] += v;
            else       C[orow + col] = v;
        }
    }
}

// ---------------------------------------------------------------------------
// Attention v2: one block per (window, head). K AND V staged in LDS as bf16
// (56.7 KB -> 2 blocks/CU, all 384 blocks resident). Q loaded straight to
// registers via 8 broadcast float4s. Scores/softmax/PV accumulate in f32.
__global__ __launch_bounds__(256) void k_attn(const float* __restrict__ QKV,
                                              const float* __restrict__ rpb,
                                              const int* __restrict__ rpi,
                                              float* __restrict__ AO,
                                              int shifted) {
    int wi   = blockIdx.x / NHEADS;
    int head = blockIdx.x % NHEADS;
    int wbase = wi * NTOK;
    __shared__ ushort_t Ks[NTOK * 34];   // pad 34: row stride 68 B (17 words, odd)
    __shared__ ushort_t Vs[NTOK * 32];
    __shared__ float    Ps[4][NTOK];
    int tid = threadIdx.x;
    for (int idx = tid; idx < NTOK * HDIM; idx += 256) {
        int j = idx >> 5, d = idx & 31;
        size_t rb = (size_t)(wbase + j) * 2304 + head * 32 + d;
        Ks[j * 34 + d] = (ushort_t)(__bfloat16_as_ushort(__float2bfloat16(QKV[rb + 768])));
        Vs[j * 32 + d] = (ushort_t)(__bfloat16_as_ushort(__float2bfloat16(QKV[rb + 1536])));
    }
    __syncthreads();
    int lane = tid & 63, wv = tid >> 6;
    int rem = wi & 7;
    int wd = rem >> 2, wh = (rem >> 1) & 1, ww = rem & 1;

    for (int i = wv; i < NTOK; i += 4) {   // 98 iterations, uniform across waves
        // Q row straight to registers (broadcast loads, 128 B)
        const float4* qp = (const float4*)(QKV + (size_t)(wbase + i) * 2304 + head * 32);
        float q[HDIM];
#pragma unroll
        for (int m = 0; m < 8; ++m) {
            float4 v = qp[m];
            q[m * 4 + 0] = v.x; q[m * 4 + 1] = v.y; q[m * 4 + 2] = v.z; q[m * 4 + 3] = v.w;
        }

        int rid_i = 0;
        if (shifted) {
            int dn = i / 49, r2 = i % 49, hn = r2 / 7, wn = r2 % 7;
            int d = wd * 8 + dn, h = wh * 7 + hn, w = ww * 7 + wn;
            rid_i = (((d < 8) ? 0 : (d < 12 ? 1 : 2)) * 3 +
                     ((h < 7) ? 0 : (h < 11 ? 1 : 2))) * 3 +
                     ((w < 7) ? 0 : (w < 11 ? 1 : 2));
        }
        float sreg[7];
        float smax = -1e30f;
#pragma unroll
        for (int t = 0; t < 7; ++t) {
            int j = lane + t * 64;
            float sc = -1e30f;
            if (j < NTOK) {
                const ushort_t* kr = Ks + j * 34;
                float acc = 0.f;
#pragma unroll
                for (int d = 0; d < HDIM; ++d) acc += q[d] * bf2f(kr[d]);
                acc *= QSCALE;
                acc += rpb[(size_t)rpi[i * NTOK + j] * NHEADS + head];
                if (shifted) {
                    int dn = j / 49, r2 = j % 49, hn = r2 / 7, wn = r2 % 7;
                    int d = wd * 8 + dn, h = wh * 7 + hn, w = ww * 7 + wn;
                    int rid_j = (((d < 8) ? 0 : (d < 12 ? 1 : 2)) * 3 +
                                 ((h < 7) ? 0 : (h < 11 ? 1 : 2))) * 3 +
                                 ((w < 7) ? 0 : (w < 11 ? 1 : 2));
                    if (rid_j != rid_i) acc -= 100.0f;
                }
                sc = acc;
            }
            sreg[t] = sc;
            smax = fmaxf(smax, sc);
        }
#pragma unroll
        for (int off = 32; off > 0; off >>= 1) smax = fmaxf(smax, __shfl_xor(smax, off));
        float ssum = 0.f;
#pragma unroll
        for (int t = 0; t < 7; ++t) {
            int j = lane + t * 64;
            if (j < NTOK) {
                float e = __expf(sreg[t] - smax);
                Ps[wv][j] = e;
                ssum += e;
            }
        }
#pragma unroll
        for (int off = 32; off > 0; off >>= 1) ssum += __shfl_xor(ssum, off);
        float inv = 1.0f / ssum;
        __syncthreads();   // Ps visible (also keeps waves aligned; counts match)
        // P @ V from LDS
        int d = lane & 31, half = lane >> 5;
        float acc = 0.f;
        for (int j = half; j < NTOK; j += 2) acc += Ps[wv][j] * bf2f(Vs[j * 32 + d]);
        acc += __shfl_xor(acc, 32);
        if (lane < 32)
            AO[(size_t)(wbase + i) * CDIM + head * 32 + d] = acc * inv;
    }
}

// ---------------------------------------------------------------------------
// Head conv2: (T,64) @ (2,64)^T + b -> gelu -> O2[t*2+p]
__global__ __launch_bounds__(256) void k_head_c2(const float* __restrict__ Y64,
                                                 const float* __restrict__ w2,
                                                 const float* __restrict__ b2,
                                                 float* __restrict__ O2) {
    int idx = blockIdx.x * 256 + threadIdx.x;
    if (idx >= T_TOK * 2) return;
    int t = idx >> 1, p = idx & 1;
    const float* yr = Y64 + (size_t)t * 64;
    float acc = b2[p];
#pragma unroll
    for (int o = 0; o < 64; ++o) acc += yr[o] * w2[p * 64 + o];
    O2[idx] = gelu_f(acc);
}

// score * weight, layout (B,2,D,H,W), float32 out
__global__ __launch_bounds__(256) void k_final(const float* __restrict__ O2,
                                               float* __restrict__ out) {
    int idx = blockIdx.x * 256 + threadIdx.x;
    if (idx >= 2 * 2 * 3136) return;
    int b = idx / 6272;
    int p = (idx / 3136) & 1;
    int s = idx % 3136;
    int t = b * 3136 + s;
    out[idx] = O2[t * 2 + p] * O2[(size_t)T_TOK * 2 + t * 2 + p];
}

// ---------------------------------------------------------------------------
extern "C" void kernel_launch(void* const* d_in, const int* in_sizes, int n_in,
                              void* d_out, int out_size, void* d_ws, size_t ws_size,
                              hipStream_t stream) {
    const float* x     = (const float*)d_in[0];
    const float* n1_g  = (const float*)d_in[1];
    const float* n1_b  = (const float*)d_in[2];
    const float* qkv_w = (const float*)d_in[3];
    const float* qkv_b = (const float*)d_in[4];
    const float* proj_w= (const float*)d_in[5];
    const float* proj_b= (const float*)d_in[6];
    const float* rpb   = (const float*)d_in[7];
    const float* n2_g  = (const float*)d_in[8];
    const float* n2_b  = (const float*)d_in[9];
    const float* fc1_w = (const float*)d_in[10];
    const float* fc1_b = (const float*)d_in[11];
    const float* fc2_w = (const float*)d_in[12];
    const float* fc2_b = (const float*)d_in[13];
    const float* hln_g = (const float*)d_in[14];
    const float* hln_b = (const float*)d_in[15];
    const float* c1_w  = (const float*)d_in[16];
    const float* c1_b  = (const float*)d_in[17];
    const float* c2_w  = (const float*)d_in[18];
    const float* c2_b  = (const float*)d_in[19];
    const int*   rpi   = (const int*)d_in[20];

    // ws layout (fp32): X | XW(=attn-out) | BIG(qkv 2304 / mlp 3072 cols) | Y64 | O2
    float* ws  = (float*)d_ws;
    float* X   = ws;
    float* XW  = X   + (size_t)T_TOK * CDIM;
    float* BIG = XW  + (size_t)T_TOK * CDIM;
    float* Y64 = BIG + (size_t)T_TOK * 3072;
    float* O2  = Y64 + (size_t)T_TOK * 64;   // total ~117 MB

    for (int br = 0; br < 2; ++br) {
        k_transpose_in<<<dim3(98, 24, 2), dim3(32, 8), 0, stream>>>(x, X);
        for (int bl = 0; bl < 2; ++bl) {
            int pb = br * 2 + bl;
            int shifted = bl;
            k_layernorm<<<T_TOK, 256, 0, stream>>>(X, XW, n1_g + pb * 768, n1_b + pb * 768, shifted ? 2 : 1);
            k_gemm<<<dim3(2304 / 64, 98), 256, 0, stream>>>(XW, qkv_w + (size_t)pb * 2304 * 768,
                                                            qkv_b + pb * 2304, BIG,
                                                            T_TOK, 2304, 768, 0, 0, 0);
            k_attn<<<NWIN * NHEADS, 256, 0, stream>>>(BIG, rpb + (size_t)pb * 2535 * 24, rpi, XW, shifted);
            k_gemm<<<dim3(768 / 64, 98), 256, 0, stream>>>(XW, proj_w + (size_t)pb * 768 * 768,
                                                           proj_b + pb * 768, X,
                                                           T_TOK, 768, 768, 0, shifted ? 2 : 1, 1);
            k_layernorm<<<T_TOK, 256, 0, stream>>>(X, XW, n2_g + pb * 768, n2_b + pb * 768, 0);
            k_gemm<<<dim3(3072 / 64, 98), 256, 0, stream>>>(XW, fc1_w + (size_t)pb * 3072 * 768,
                                                            fc1_b + pb * 3072, BIG,
                                                            T_TOK, 3072, 768, 1, 0, 0);
            k_gemm<<<dim3(768 / 64, 98), 256, 0, stream>>>(BIG, fc2_w + (size_t)pb * 768 * 3072,
                                                           fc2_b + pb * 768, X,
                                                           T_TOK, 768, 3072, 0, 0, 1);
        }
        k_layernorm<<<T_TOK, 256, 0, stream>>>(X, XW, hln_g + br * 768, hln_b + br * 768, 0);
        k_gemm<<<dim3(1, 98), 256, 0, stream>>>(XW, c1_w + (size_t)br * 64 * 768,
                                                c1_b + br * 64, Y64,
                                                T_TOK, 64, 768, 1, 0, 0);
        k_head_c2<<<(T_TOK * 2 + 255) / 256, 256, 0, stream>>>(Y64, c2_w + br * 128, c2_b + br * 2,
                                                               O2 + (size_t)br * T_TOK * 2);
    }
    k_final<<<(2 * 2 * 3136 + 255) / 256, 256, 0, stream>>>(O2, (float*)d_out);
}

// Round 7
// 4280.461 us; speedup vs baseline: 5.6080x; 2.3361x over previous
//
#include <hip/hip_runtime.h>
#include <hip/hip_bf16.h>

// Problem constants
#define T_TOK 6272      // B*D*H*W tokens (2*16*14*14)
#define CDIM  768
#define NTOK  392       // tokens per window (8*7*7)
#define NWIN  16        // total windows (B=2 * 8)
#define NHEADS 24
#define HDIM  32
#define QSCALE 0.17677669529663687f  // 32^-0.5

typedef unsigned short ushort_t;
typedef __attribute__((ext_vector_type(8))) short bf16x8;
typedef __attribute__((ext_vector_type(4))) float f32x4;

__device__ __forceinline__ float bf2f(ushort_t h) {
    union { unsigned int u; float f; } v; v.u = ((unsigned int)h) << 16; return v.f;
}
__device__ __forceinline__ ushort_t f2bf(float f) {
    return __bfloat16_as_ushort(__float2bfloat16(f));
}
__device__ __forceinline__ float gelu_f(float x) {
    return 0.5f * x * (1.0f + erff(x * 0.70710678118654752f));
}

// ---------------------------------------------------------------------------
// (B,C,D,H,W) f32 -> X[t][c] f32
__global__ __launch_bounds__(256) void k_transpose_in(const float* __restrict__ x,
                                                      float* __restrict__ X) {
    __shared__ float tile[32][33];
    int b  = blockIdx.z;
    int s0 = blockIdx.x * 32, c0 = blockIdx.y * 32;
    int tx = threadIdx.x, ty = threadIdx.y;
#pragma unroll
    for (int r = 0; r < 4; ++r)
        tile[ty + r * 8][tx] = x[((size_t)b * 768 + c0 + ty + r * 8) * 3136 + s0 + tx];
    __syncthreads();
#pragma unroll
    for (int r = 0; r < 4; ++r)
        X[((size_t)b * 3136 + s0 + ty + r * 8) * 768 + c0 + tx] = tile[tx][ty + r * 8];
}

// ---------------------------------------------------------------------------
// f32 -> bf16 elementwise (weight conversion)
__global__ __launch_bounds__(256) void k_f2b(const float* __restrict__ s,
                                             ushort_t* __restrict__ d, int n) {
    int i = blockIdx.x * 256 + threadIdx.x;
    if (i < n) d[i] = f2bf(s[i]);
}

// ---------------------------------------------------------------------------
// LayerNorm, bf16 output. mode 0: identity rows. mode 1: window-gather.
// mode 2: window-gather with roll(-4,-3,-3) folded in.
__global__ __launch_bounds__(256) void k_ln_bf(const float* __restrict__ X,
                                               ushort_t* __restrict__ Y,
                                               const float* __restrict__ g,
                                               const float* __restrict__ bta,
                                               int mode) {
    int row = blockIdx.x;
    int src = row;
    if (mode != 0) {
        int wi = row / NTOK, n = row % NTOK;
        int b = wi >> 3, rem = wi & 7;
        int wd = rem >> 2, wh = (rem >> 1) & 1, ww = rem & 1;
        int dn = n / 49, r2 = n % 49, hn = r2 / 7, wn = r2 % 7;
        int d = wd * 8 + dn, h = wh * 7 + hn, w = ww * 7 + wn;
        if (mode == 2) { d = (d + 4) & 15; h = (h + 3) % 14; w = (w + 3) % 14; }
        src = (b * 16 + d) * 196 + h * 14 + w;
    }
    const float* xr = X + (size_t)src * CDIM;
    int tid = threadIdx.x;
    float v0 = xr[tid], v1 = xr[tid + 256], v2 = xr[tid + 512];
    float s = v0 + v1 + v2;
    float q = v0 * v0 + v1 * v1 + v2 * v2;
    __shared__ float red[8];
#pragma unroll
    for (int off = 32; off > 0; off >>= 1) {
        s += __shfl_down(s, off);
        q += __shfl_down(q, off);
    }
    int lane = tid & 63, wv = tid >> 6;
    if (lane == 0) { red[wv] = s; red[4 + wv] = q; }
    __syncthreads();
    float ts = red[0] + red[1] + red[2] + red[3];
    float tq = red[4] + red[5] + red[6] + red[7];
    float mu  = ts * (1.0f / 768.0f);
    float var = tq * (1.0f / 768.0f) - mu * mu;
    float rstd = rsqrtf(var + 1e-5f);
    ushort_t* yr = Y + (size_t)row * CDIM;
    yr[tid]       = f2bf((v0 - mu) * rstd * g[tid]       + bta[tid]);
    yr[tid + 256] = f2bf((v1 - mu) * rstd * g[tid + 256] + bta[tid + 256]);
    yr[tid + 512] = f2bf((v2 - mu) * rstd * g[tid + 512] + bta[tid + 512]);
}

// LayerNorm, f32 output, identity rows (head path only).
__global__ __launch_bounds__(256) void k_ln_f32(const float* __restrict__ X,
                                                float* __restrict__ Y,
                                                const float* __restrict__ g,
                                                const float* __restrict__ bta) {
    int row = blockIdx.x, tid = threadIdx.x;
    const float* xr = X + (size_t)row * CDIM;
    float v0 = xr[tid], v1 = xr[tid + 256], v2 = xr[tid + 512];
    float s = v0 + v1 + v2;
    float q = v0 * v0 + v1 * v1 + v2 * v2;
    __shared__ float red[8];
#pragma unroll
    for (int off = 32; off > 0; off >>= 1) {
        s += __shfl_down(s, off);
        q += __shfl_down(q, off);
    }
    int lane = tid & 63, wv = tid >> 6;
    if (lane == 0) { red[wv] = s; red[4 + wv] = q; }
    __syncthreads();
    float ts = red[0] + red[1] + red[2] + red[3];
    float tq = red[4] + red[5] + red[6] + red[7];
    float mu  = ts * (1.0f / 768.0f);
    float var = tq * (1.0f / 768.0f) - mu * mu;
    float rstd = rsqrtf(var + 1e-5f);
    float* yr = Y + (size_t)row * CDIM;
    yr[tid]       = (v0 - mu) * rstd * g[tid]       + bta[tid];
    yr[tid + 256] = (v1 - mu) * rstd * g[tid + 256] + bta[tid + 256];
    yr[tid + 512] = (v2 - mu) * rstd * g[tid + 512] + bta[tid + 512];
}

// ---------------------------------------------------------------------------
// MFMA GEMM: C[M,N] = act(A[M,K] @ W[N,K]^T + bias)
// A, W bf16 row-major [rows][K]; 128x128 tile, BK=32, 4 waves (2x2 quads),
// each wave a 4x4 grid of 16x16x32 MFMAs. Staging: bf16x8 global loads ->
// registers -> ds_write (NO global_load_lds this round — fault bisection).
// LDS layout: tile[row][32] contiguous. outbf: bf16 out to Cb. remap 1/2:
// scatter window rows to image rows (2 = roll +(4,3,3)). accum: += into Cf.
__global__ __launch_bounds__(256) void k_gemm_mfma(const ushort_t* __restrict__ A,
                                                   const ushort_t* __restrict__ W,
                                                   const float* __restrict__ bias,
                                                   float* __restrict__ Cf,
                                                   ushort_t* __restrict__ Cb,
                                                   int M, int N, int K,
                                                   int act, int remap, int accum, int outbf) {
    __shared__ ushort_t As[128 * 32];
    __shared__ ushort_t Bs[128 * 32];
    int tid = threadIdx.x, lane = tid & 63, w = tid >> 6;
    int wm = w >> 1, wn = w & 1;
    int m0 = blockIdx.y * 128, n0 = blockIdx.x * 128;

    // staging: thread covers LDS elements [e0, e0+8) and [e1, e1+8) per matrix
    int e0 = tid * 8;            // rows 0..63   (row = e>>5, kk = e&31)
    int e1 = 2048 + tid * 8;     // rows 64..127
    int r0 = e0 >> 5, kk0 = e0 & 31;
    int r1 = e1 >> 5, kk1 = e1 & 31;
    const ushort_t* gA0 = A + (size_t)(m0 + r0) * K + kk0;
    const ushort_t* gA1 = A + (size_t)(m0 + r1) * K + kk1;
    const ushort_t* gB0 = W + (size_t)(n0 + r0) * K + kk0;
    const ushort_t* gB1 = W + (size_t)(n0 + r1) * K + kk1;

    f32x4 acc[4][4];
#pragma unroll
    for (int mi = 0; mi < 4; ++mi)
#pragma unroll
        for (int ni = 0; ni < 4; ++ni) acc[mi][ni] = (f32x4){0.f, 0.f, 0.f, 0.f};

    for (int k0 = 0; k0 < K; k0 += 32) {
        bf16x8 a0 = *(const bf16x8*)(gA0 + k0);
        bf16x8 a1 = *(const bf16x8*)(gA1 + k0);
        bf16x8 b0 = *(const bf16x8*)(gB0 + k0);
        bf16x8 b1 = *(const bf16x8*)(gB1 + k0);
        __syncthreads();             // prev iteration's frag reads done
        *(bf16x8*)&As[e0] = a0;
        *(bf16x8*)&As[e1] = a1;
        *(bf16x8*)&Bs[e0] = b0;
        *(bf16x8*)&Bs[e1] = b1;
        __syncthreads();             // stores visible
        bf16x8 af[4], bg[4];
#pragma unroll
        for (int mi = 0; mi < 4; ++mi)
            af[mi] = *(const bf16x8*)&As[(wm * 64 + mi * 16 + (lane & 15)) * 32 + (lane >> 4) * 8];
#pragma unroll
        for (int ni = 0; ni < 4; ++ni)
            bg[ni] = *(const bf16x8*)&Bs[(wn * 64 + ni * 16 + (lane & 15)) * 32 + (lane >> 4) * 8];
#pragma unroll
        for (int mi = 0; mi < 4; ++mi)
#pragma unroll
            for (int ni = 0; ni < 4; ++ni)
                acc[mi][ni] = __builtin_amdgcn_mfma_f32_16x16x32_bf16(af[mi], bg[ni], acc[mi][ni], 0, 0, 0);
    }

    int cl = lane & 15, rq = lane >> 4;
#pragma unroll
    for (int mi = 0; mi < 4; ++mi) {
#pragma unroll
        for (int ni = 0; ni < 4; ++ni) {
            int gcol = n0 + wn * 64 + ni * 16 + cl;
            float bv = bias[gcol];
#pragma unroll
            for (int i = 0; i < 4; ++i) {
                int r = m0 + wm * 64 + mi * 16 + rq * 4 + i;
                float v = acc[mi][ni][i] + bv;
                if (act) v = gelu_f(v);
                if (outbf) {
                    Cb[(size_t)r * N + gcol] = f2bf(v);
                } else {
                    size_t orow;
                    if (remap == 0) {
                        orow = (size_t)r * N;
                    } else {
                        int wi = r / NTOK, n = r % NTOK;
                        int b = wi >> 3, rem = wi & 7;
                        int wd = rem >> 2, wh = (rem >> 1) & 1, ww = rem & 1;
                        int dn = n / 49, r2 = n % 49, hn = r2 / 7, wnn = r2 % 7;
                        int d = wd * 8 + dn, h = wh * 7 + hn, ww2 = ww * 7 + wnn;
                        if (remap == 2) { d = (d + 4) & 15; h = (h + 3) % 14; ww2 = (ww2 + 3) % 14; }
                        orow = (size_t)((b * 16 + d) * 196 + h * 14 + ww2) * N;
                    }
                    if (accum) Cf[orow + gcol] += v;
                    else       Cf[orow + gcol] = v;
                }
            }
        }
    }
}

// ---------------------------------------------------------------------------
// f32 GEMM (head c1 only, N=64): 64x64x16 tile, 4x4 microtile.
__global__ __launch_bounds__(256) void k_gemm_f32(const float* __restrict__ A,
                                                  const float* __restrict__ W,
                                                  const float* __restrict__ bias,
                                                  float* __restrict__ C,
                                                  int M, int N, int K, int act) {
    __shared__ float As[16][64];
    __shared__ float Bs[16][64];
    int tid = threadIdx.x;
    int m0 = blockIdx.y * 64, n0 = blockIdx.x * 64;
    int lrow = tid >> 2;
    int lk   = (tid & 3) * 4;
    const float* aptr = A + (size_t)(m0 + lrow) * K + lk;
    const float* wptr = W + (size_t)(n0 + lrow) * K + lk;
    int tx = tid & 15, ty = tid >> 4;
    float acc[4][4] = {};
    for (int kt = 0; kt < K; kt += 16) {
        float4 av = *(const float4*)(aptr + kt);
        float4 wv4 = *(const float4*)(wptr + kt);
        As[lk + 0][lrow] = av.x;  As[lk + 1][lrow] = av.y;
        As[lk + 2][lrow] = av.z;  As[lk + 3][lrow] = av.w;
        Bs[lk + 0][lrow] = wv4.x; Bs[lk + 1][lrow] = wv4.y;
        Bs[lk + 2][lrow] = wv4.z; Bs[lk + 3][lrow] = wv4.w;
        __syncthreads();
#pragma unroll
        for (int k = 0; k < 16; ++k) {
            float4 a = *(const float4*)&As[k][ty * 4];
            float4 b = *(const float4*)&Bs[k][tx * 4];
            float avv[4] = {a.x, a.y, a.z, a.w};
            float bvv[4] = {b.x, b.y, b.z, b.w};
#pragma unroll
            for (int i = 0; i < 4; ++i)
#pragma unroll
                for (int j = 0; j < 4; ++j)
                    acc[i][j] += avv[i] * bvv[j];
        }
        __syncthreads();
    }
    float bvals[4];
#pragma unroll
    for (int j = 0; j < 4; ++j) bvals[j] = bias[n0 + tx * 4 + j];
#pragma unroll
    for (int i = 0; i < 4; ++i) {
        int r = m0 + ty * 4 + i;
#pragma unroll
        for (int j = 0; j < 4; ++j) {
            float v = acc[i][j] + bvals[j];
            if (act) v = gelu_f(v);
            C[(size_t)r * N + n0 + tx * 4 + j] = v;
        }
    }
}

// ---------------------------------------------------------------------------
// Attention: one block per (window, head). K/V staged in LDS bf16.
// Q f32 broadcast to registers. bf16 output. PV with 4 independent accs.
__global__ __launch_bounds__(256) void k_attn(const float* __restrict__ QKV,
                                              const float* __restrict__ rpb,
                                              const int* __restrict__ rpi,
                                              ushort_t* __restrict__ AO,
                                              int shifted) {
    int wi   = blockIdx.x / NHEADS;
    int head = blockIdx.x % NHEADS;
    int wbase = wi * NTOK;
    __shared__ ushort_t Ks[NTOK * 34];
    __shared__ ushort_t Vs[NTOK * 32];
    __shared__ float    Ps[4][NTOK];
    int tid = threadIdx.x;
    for (int idx = tid; idx < NTOK * HDIM; idx += 256) {
        int j = idx >> 5, d = idx & 31;
        size_t rb = (size_t)(wbase + j) * 2304 + head * 32 + d;
        Ks[j * 34 + d] = f2bf(QKV[rb + 768]);
        Vs[j * 32 + d] = f2bf(QKV[rb + 1536]);
    }
    __syncthreads();
    int lane = tid & 63, wv = tid >> 6;
    int rem = wi & 7;
    int wd = rem >> 2, wh = (rem >> 1) & 1, ww = rem & 1;

    for (int i = wv; i < NTOK; i += 4) {
        const float4* qp = (const float4*)(QKV + (size_t)(wbase + i) * 2304 + head * 32);
        float q[HDIM];
#pragma unroll
        for (int m = 0; m < 8; ++m) {
            float4 v = qp[m];
            q[m * 4 + 0] = v.x; q[m * 4 + 1] = v.y; q[m * 4 + 2] = v.z; q[m * 4 + 3] = v.w;
        }
        int rid_i = 0;
        if (shifted) {
            int dn = i / 49, r2 = i % 49, hn = r2 / 7, wn = r2 % 7;
            int d = wd * 8 + dn, h = wh * 7 + hn, w = ww * 7 + wn;
            rid_i = (((d < 8) ? 0 : (d < 12 ? 1 : 2)) * 3 +
                     ((h < 7) ? 0 : (h < 11 ? 1 : 2))) * 3 +
                     ((w < 7) ? 0 : (w < 11 ? 1 : 2));
        }
        float sreg[7];
        float smax = -1e30f;
#pragma unroll
        for (int t = 0; t < 7; ++t) {
            int j = lane + t * 64;
            float sc = -1e30f;
            if (j < NTOK) {
                const ushort_t* kr = Ks + j * 34;
                float acc = 0.f;
#pragma unroll
                for (int d = 0; d < HDIM; ++d) acc += q[d] * bf2f(kr[d]);
                acc *= QSCALE;
                acc += rpb[(size_t)rpi[i * NTOK + j] * NHEADS + head];
                if (shifted) {
                    int dn = j / 49, r2 = j % 49, hn = r2 / 7, wn = r2 % 7;
                    int d = wd * 8 + dn, h = wh * 7 + hn, w = ww * 7 + wn;
                    int rid_j = (((d < 8) ? 0 : (d < 12 ? 1 : 2)) * 3 +
                                 ((h < 7) ? 0 : (h < 11 ? 1 : 2))) * 3 +
                                 ((w < 7) ? 0 : (w < 11 ? 1 : 2));
                    if (rid_j != rid_i) acc -= 100.0f;
                }
                sc = acc;
            }
            sreg[t] = sc;
            smax = fmaxf(smax, sc);
        }
#pragma unroll
        for (int off = 32; off > 0; off >>= 1) smax = fmaxf(smax, __shfl_xor(smax, off));
        float ssum = 0.f;
#pragma unroll
        for (int t = 0; t < 7; ++t) {
            int j = lane + t * 64;
            if (j < NTOK) {
                float e = __expf(sreg[t] - smax);
                Ps[wv][j] = e;
                ssum += e;
            }
        }
#pragma unroll
        for (int off = 32; off > 0; off >>= 1) ssum += __shfl_xor(ssum, off);
        float inv = 1.0f / ssum;
        __syncthreads();
        // P @ V, ILP 4 (392 = 49 * 8)
        int d = lane & 31, half = lane >> 5;
        float a0 = 0.f, a1 = 0.f, a2 = 0.f, a3 = 0.f;
        for (int j = half; j < NTOK; j += 8) {
            a0 += Ps[wv][j]     * bf2f(Vs[(j)     * 32 + d]);
            a1 += Ps[wv][j + 2] * bf2f(Vs[(j + 2) * 32 + d]);
            a2 += Ps[wv][j + 4] * bf2f(Vs[(j + 4) * 32 + d]);
            a3 += Ps[wv][j + 6] * bf2f(Vs[(j + 6) * 32 + d]);
        }
        float acc = (a0 + a1) + (a2 + a3);
        acc += __shfl_xor(acc, 32);
        if (lane < 32)
            AO[(size_t)(wbase + i) * CDIM + head * 32 + d] = f2bf(acc * inv);
    }
}

// ---------------------------------------------------------------------------
__global__ __launch_bounds__(256) void k_head_c2(const float* __restrict__ Y64,
                                                 const float* __restrict__ w2,
                                                 const float* __restrict__ b2,
                                                 float* __restrict__ O2) {
    int idx = blockIdx.x * 256 + threadIdx.x;
    if (idx >= T_TOK * 2) return;
    int t = idx >> 1, p = idx & 1;
    const float* yr = Y64 + (size_t)t * 64;
    float acc = b2[p];
#pragma unroll
    for (int o = 0; o < 64; ++o) acc += yr[o] * w2[p * 64 + o];
    O2[idx] = gelu_f(acc);
}

__global__ __launch_bounds__(256) void k_final(const float* __restrict__ O2,
                                               float* __restrict__ out) {
    int idx = blockIdx.x * 256 + threadIdx.x;
    if (idx >= 2 * 2 * 3136) return;
    int b = idx / 6272;
    int p = (idx / 3136) & 1;
    int s = idx % 3136;
    int t = b * 3136 + s;
    out[idx] = O2[t * 2 + p] * O2[(size_t)T_TOK * 2 + t * 2 + p];
}

// ---------------------------------------------------------------------------
extern "C" void kernel_launch(void* const* d_in, const int* in_sizes, int n_in,
                              void* d_out, int out_size, void* d_ws, size_t ws_size,
                              hipStream_t stream) {
    const float* x     = (const float*)d_in[0];
    const float* n1_g  = (const float*)d_in[1];
    const float* n1_b  = (const float*)d_in[2];
    const float* qkv_w = (const float*)d_in[3];
    const float* qkv_b = (const float*)d_in[4];
    const float* proj_w= (const float*)d_in[5];
    const float* proj_b= (const float*)d_in[6];
    const float* rpb   = (const float*)d_in[7];
    const float* n2_g  = (const float*)d_in[8];
    const float* n2_b  = (const float*)d_in[9];
    const float* fc1_w = (const float*)d_in[10];
    const float* fc1_b = (const float*)d_in[11];
    const float* fc2_w = (const float*)d_in[12];
    const float* fc2_b = (const float*)d_in[13];
    const float* hln_g = (const float*)d_in[14];
    const float* hln_b = (const float*)d_in[15];
    const float* c1_w  = (const float*)d_in[16];
    const float* c1_b  = (const float*)d_in[17];
    const float* c2_w  = (const float*)d_in[18];
    const float* c2_b  = (const float*)d_in[19];
    const int*   rpi   = (const int*)d_in[20];

    // ws: X f32 | BIG f32 (qkv; bf16 mlp-hidden / head-LN f32 overlay) | Y64 | O2 | XWb bf16 | WB bf16
    float* ws   = (float*)d_ws;
    float* X    = ws;                                  // 4,816,896 f32
    float* BIG  = X + (size_t)T_TOK * CDIM;            // 14,450,688 f32
    float* Y64  = BIG + (size_t)T_TOK * 2304;          // 401,408 f32
    float* O2   = Y64 + (size_t)T_TOK * 64;            // 25,088 f32
    ushort_t* XWb = (ushort_t*)(O2 + 2 * T_TOK * 2);
    ushort_t* WB  = XWb + (size_t)T_TOK * CDIM;
    ushort_t* WBq = WB;
    ushort_t* WBp = WBq + (size_t)2304 * 768;
    ushort_t* WB1 = WBp + (size_t)768 * 768;
    ushort_t* WB2 = WB1 + (size_t)3072 * 768;
    ushort_t* BIGb = (ushort_t*)BIG;                   // bf16 mlp hidden overlay

    const int NQ = 2304 * 768, NP = 768 * 768, N1 = 3072 * 768, N2 = 768 * 3072;

    for (int br = 0; br < 2; ++br) {
        k_transpose_in<<<dim3(98, 24, 2), dim3(32, 8), 0, stream>>>(x, X);
        for (int bl = 0; bl < 2; ++bl) {
            int pb = br * 2 + bl;
            int shifted = bl;
            // weight conversion f32 -> bf16
            k_f2b<<<(NQ + 255) / 256, 256, 0, stream>>>(qkv_w + (size_t)pb * NQ, WBq, NQ);
            k_f2b<<<(NP + 255) / 256, 256, 0, stream>>>(proj_w + (size_t)pb * NP, WBp, NP);
            k_f2b<<<(N1 + 255) / 256, 256, 0, stream>>>(fc1_w + (size_t)pb * N1, WB1, N1);
            k_f2b<<<(N2 + 255) / 256, 256, 0, stream>>>(fc2_w + (size_t)pb * N2, WB2, N2);

            k_ln_bf<<<T_TOK, 256, 0, stream>>>(X, XWb, n1_g + pb * 768, n1_b + pb * 768, shifted ? 2 : 1);
            k_gemm_mfma<<<dim3(18, 49), 256, 0, stream>>>(XWb, WBq, qkv_b + pb * 2304,
                                                          BIG, (ushort_t*)0,
                                                          T_TOK, 2304, 768, 0, 0, 0, 0);
            k_attn<<<NWIN * NHEADS, 256, 0, stream>>>(BIG, rpb + (size_t)pb * 2535 * 24, rpi, XWb, shifted);
            k_gemm_mfma<<<dim3(6, 49), 256, 0, stream>>>(XWb, WBp, proj_b + pb * 768,
                                                         X, (ushort_t*)0,
                                                         T_TOK, 768, 768, 0, shifted ? 2 : 1, 1, 0);
            k_ln_bf<<<T_TOK, 256, 0, stream>>>(X, XWb, n2_g + pb * 768, n2_b + pb * 768, 0);
            k_gemm_mfma<<<dim3(24, 49), 256, 0, stream>>>(XWb, WB1, fc1_b + pb * 3072,
                                                          (float*)0, BIGb,
                                                          T_TOK, 3072, 768, 1, 0, 0, 1);
            k_gemm_mfma<<<dim3(6, 49), 256, 0, stream>>>(BIGb, WB2, fc2_b + pb * 768,
                                                         X, (ushort_t*)0,
                                                         T_TOK, 768, 3072, 0, 0, 1, 0);
        }
        // head: all f32 (BIG free here, reuse for LN output)
        k_ln_f32<<<T_TOK, 256, 0, stream>>>(X, BIG, hln_g + br * 768, hln_b + br * 768);
        k_gemm_f32<<<dim3(1, 98), 256, 0, stream>>>(BIG, c1_w + (size_t)br * 64 * 768,
                                                    c1_b + br * 64, Y64,
                                                    T_TOK, 64, 768, 1);
        k_head_c2<<<(T_TOK * 2 + 255) / 256, 256, 0, stream>>>(Y64, c2_w + br * 128, c2_b + br * 2,
                                                               O2 + (size_t)br * T_TOK * 2);
    }
    k_final<<<(2 * 2 * 3136 + 255) / 256, 256, 0, stream>>>(O2, (float*)d_out);
}